// Round 1
// baseline (4215.761 us; speedup 1.0000x reference)
//
#include <hip/hip_runtime.h>

#define HIDDEN 256
#define TENC 336
#define HORIZ 168
#define BSZ 1024
#define BH (BSZ*HIDDEN)

typedef _Float16 f16;
typedef f16 f16x8 __attribute__((ext_vector_type(8)));
typedef float f32x4 __attribute__((ext_vector_type(4)));
typedef unsigned int u32;
typedef unsigned long long u64;

// d_ws layout
#define H0_OFF 0
#define H1_OFF (2*BH*2)                 // 1 MiB
#define PRED_OFF (H1_OFF + 2*BH*2)      // 2 MiB
#define FLAG_OFF (PRED_OFF + 2*BSZ*4)   // +8 KiB
#define WS_TOTAL (FLAG_OFF + 256*128)   // +32 KiB

// LDS layout (dynamic)
#define LDS_A0 0
#define LDS_A1 32768
#define LDS_X0 65536
#define LDS_X1 81920
#define LDS_SM 98304
#define LDS_TOTAL (LDS_SM + 1024)

__device__ __forceinline__ float sigm(float x){ return 1.0f/(1.0f+__expf(-x)); }
__device__ __forceinline__ float tanh_f(float x){ return 2.0f/(1.0f+__expf(-2.0f*x)) - 1.0f; }

__device__ __forceinline__ u64 ald64(const f16* p){
  return __hip_atomic_load((const u64*)p, __ATOMIC_RELAXED, __HIP_MEMORY_SCOPE_AGENT);
}
__device__ __forceinline__ u32 ald32(const u32* p){
  return __hip_atomic_load(p, __ATOMIC_RELAXED, __HIP_MEMORY_SCOPE_AGENT);
}
__device__ __forceinline__ float aldf(const float* p){
  return __hip_atomic_load(p, __ATOMIC_RELAXED, __HIP_MEMORY_SCOPE_AGENT);
}
__device__ __forceinline__ void ast32(u32* p, u32 v){
  __hip_atomic_store(p, v, __ATOMIC_RELAXED, __HIP_MEMORY_SCOPE_AGENT);
}
__device__ __forceinline__ void astf(float* p, float v){
  __hip_atomic_store(p, v, __ATOMIC_RELAXED, __HIP_MEMORY_SCOPE_AGENT);
}

// one B-fragment (16 gate-cols x 32 k) for v_mfma_f32_16x16x32_f16:
// lane holds W[grow(col=l&15)][k .. k+7], k = kt*32 + 8*(l>>4)
__device__ __forceinline__ f16x8 loadWfrag(const float* W, int grow, int k){
  const float* p = W + grow*HIDDEN + k;
  float4 lo = *(const float4*)p;
  float4 hi = *(const float4*)(p+4);
  f16x8 r;
  r[0]=(f16)lo.x; r[1]=(f16)lo.y; r[2]=(f16)lo.z; r[3]=(f16)lo.w;
  r[4]=(f16)hi.x; r[5]=(f16)hi.y; r[6]=(f16)hi.z; r[7]=(f16)hi.w;
  return r;
}

// stage one 64x256 f16 h-tile from global (agent-coherent) into LDS in
// MFMA-A-fragment-linear layout: slot s=(kt*4+mt)*64+lane, 16B per slot.
__device__ __forceinline__ void stage_tile(char* dst, const f16* src_base, int g, int tid){
  #pragma unroll
  for (int i=0;i<4;++i){
    int s = tid + 512*i;
    int l = s & 63, f = s >> 6;
    int kt = f >> 2, mt = f & 3;
    int row = g*64 + mt*16 + (l&15);
    int k = kt*32 + 8*(l>>4);
    const f16* src = src_base + row*HIDDEN + k;
    u64 a = ald64(src), b = ald64(src+4);
    *(u64*)(dst + s*16) = a;
    *(u64*)(dst + s*16 + 8) = b;
  }
}

__device__ __forceinline__ void cellpair(const float* X, const float* bs, const float* wih, float xr,
                                         int crow, int dp, float& ca, float& cb, float& hA, float& hB){
  float iA = X[(0*64+crow)*16+dp  ] + bs[dp]      + xr*wih[dp];
  float iB = X[(0*64+crow)*16+dp+1] + bs[dp+1]    + xr*wih[dp+1];
  float fA = X[(1*64+crow)*16+dp  ] + bs[16+dp]   + xr*wih[16+dp];
  float fB = X[(1*64+crow)*16+dp+1] + bs[16+dp+1] + xr*wih[16+dp+1];
  float gA = X[(2*64+crow)*16+dp  ] + bs[32+dp]   + xr*wih[32+dp];
  float gB = X[(2*64+crow)*16+dp+1] + bs[32+dp+1] + xr*wih[32+dp+1];
  float oA = X[(3*64+crow)*16+dp  ] + bs[48+dp]   + xr*wih[48+dp];
  float oB = X[(3*64+crow)*16+dp+1] + bs[48+dp+1] + xr*wih[48+dp+1];
  ca = sigm(fA)*ca + sigm(iA)*tanh_f(gA);
  cb = sigm(fB)*cb + sigm(iB)*tanh_f(gB);
  hA = sigm(oA)*tanh_f(ca);
  hB = sigm(oB)*tanh_f(cb);
}

__device__ __forceinline__ void storeh(f16* base, int rowg, int col, float hA, float hB){
  u32 pk = (u32)__builtin_bit_cast(unsigned short, (f16)hA)
         | ((u32)__builtin_bit_cast(unsigned short, (f16)hB) << 16);
  __hip_atomic_store((u32*)(base + rowg*HIDDEN + col), pk, __ATOMIC_RELAXED, __HIP_MEMORY_SCOPE_AGENT);
}

// 16-CU group barrier: per-CU flag line + poll (bounded: never hangs)
__device__ __forceinline__ void gbar(u32* flags, int g, int j, int lane, int tid, u32 ev){
  __syncthreads();   // drains each wave's vmcnt (h stores complete) before flag
  if (tid == 0) ast32(&flags[(g*16 + j)*32], ev);
  const u32* sp = &flags[(g*16 + (lane&15))*32];
  bool done = false;
  for (int it = 0; it < (1<<16) && !done; ++it){
    u32 v = ald32(sp);
    done = (__all((int)(v >= ev)) != 0);
  }
}

struct P {
  const float *x;
  const float *eWih0,*eWhh0,*eBih0,*eBhh0,*eWih1,*eWhh1,*eBih1,*eBhh1;
  const float *dWih0,*dWhh0,*dBih0,*dBhh0,*dWih1,*dWhh1,*dBih1,*dBhh1;
  const float *fcW,*fcB;
  float* out;
  char* ws;
};

__global__ void initk(char* ws){
  u32* p = (u32*)ws;
  size_t total = (size_t)WS_TOTAL / 4;
  for (size_t k = (size_t)blockIdx.x*blockDim.x + threadIdx.x; k < total;
       k += (size_t)gridDim.x*blockDim.x) p[k] = 0u;
}

__global__ __launch_bounds__(512, 2) void lstm_main(P p){
  const int tid  = threadIdx.x;
  const int lane = tid & 63;
  const int w    = tid >> 6;      // wave 0..7
  const int n    = w & 3;         // gate type (i,f,g,o)
  const int mh   = w >> 2;        // row-half 0/1
  const int blk  = blockIdx.x;
  const int g    = blk & 15;      // row group (same-XCD under %8 round robin)
  const int j    = blk >> 4;      // gate-slice member 0..15

  extern __shared__ __align__(16) char smem[];
  char*  A0 = smem + LDS_A0;
  char*  A1 = smem + LDS_A1;
  float* X0 = (float*)(smem + LDS_X0);
  float* X1 = (float*)(smem + LDS_X1);
  float* wih0s = (float*)(smem + LDS_SM);  // [64] gate-major
  float* b0s   = wih0s + 64;               // [64]
  float* b1s   = wih0s + 128;              // [64]
  float* fcWs  = wih0s + 192;              // [16]
  float* fcbs  = wih0s + 208;              // [1]

  f16*   h0buf = (f16*)(p.ws + H0_OFF);
  f16*   h1buf = (f16*)(p.ws + H1_OFF);
  float* predb = (float*)(p.ws + PRED_OFF);
  u32*   flags = (u32*)(p.ws + FLAG_OFF);

  const int crow = tid >> 3;           // 0..63 row in group
  const int dp   = (tid & 7) * 2;      // dim pair in slice
  const int rowg = g*64 + crow;        // global batch row
  const int cold = j*16 + dp;          // global h column of this thread's pair

  float c0a=0.f, c0b=0.f, c1a=0.f, c1b=0.f;

  // ---- encoder tables ----
  if (tid < 64){
    int gt = tid >> 4, d = tid & 15;
    int grow = gt*256 + j*16 + d;
    wih0s[tid] = p.eWih0[grow];
    b0s[tid] = p.eBih0[grow] + p.eBhh0[grow];
    b1s[tid] = p.eBih1[grow] + p.eBhh1[grow];
  }
  if (tid < 16) fcWs[tid] = p.fcW[j*16 + tid];
  if (tid == 0) fcbs[0] = p.fcB[0];

  // ---- encoder weight fragments (VGPR-resident) ----
  f16x8 B0[8], B1i[8], B1h[8];
  {
    int grow = n*256 + j*16 + (lane & 15);
    int kb = 8*(lane>>4);
    #pragma unroll
    for (int kt=0; kt<8; ++kt){
      B0[kt]  = loadWfrag(p.eWhh0, grow, kt*32 + kb);
      B1i[kt] = loadWfrag(p.eWih1, grow, kt*32 + kb);
      B1h[kt] = loadWfrag(p.eWhh1, grow, kt*32 + kb);
    }
  }
  __syncthreads();

  u32 ev = 0;

  // ================= ENCODER: round r computes cell0(r) and cell1(r-1) ======
  for (int r = 0; r <= TENC; ++r){
    stage_tile(A0, h0buf + ((r+1)&1)*BH, g, tid);   // h0(r-1)
    stage_tile(A1, h1buf + (r&1)*BH,     g, tid);   // h1(r-2)
    __syncthreads();

    f32x4 acc0[2] = {{0.f,0.f,0.f,0.f},{0.f,0.f,0.f,0.f}};
    f32x4 acc1[2] = {{0.f,0.f,0.f,0.f},{0.f,0.f,0.f,0.f}};
    #pragma unroll
    for (int kt=0; kt<8; ++kt){
      #pragma unroll
      for (int m=0; m<2; ++m){
        f16x8 a = *(const f16x8*)(A0 + ((kt*4 + (mh*2+m))*64 + lane)*16);
        acc0[m] = __builtin_amdgcn_mfma_f32_16x16x32_f16(a, B0[kt],  acc0[m], 0,0,0);
        acc1[m] = __builtin_amdgcn_mfma_f32_16x16x32_f16(a, B1i[kt], acc1[m], 0,0,0);
      }
    }
    #pragma unroll
    for (int kt=0; kt<8; ++kt){
      #pragma unroll
      for (int m=0; m<2; ++m){
        f16x8 a = *(const f16x8*)(A1 + ((kt*4 + (mh*2+m))*64 + lane)*16);
        acc1[m] = __builtin_amdgcn_mfma_f32_16x16x32_f16(a, B1h[kt], acc1[m], 0,0,0);
      }
    }

    #pragma unroll
    for (int m=0; m<2; ++m){
      int rb = mh*32 + m*16 + 4*(lane>>4);
      #pragma unroll
      for (int q=0; q<4; ++q){
        X0[(n*64 + rb + q)*16 + (lane&15)] = acc0[m][q];
        X1[(n*64 + rb + q)*16 + (lane&15)] = acc1[m][q];
      }
    }
    __syncthreads();

    if (r < TENC){
      float xr = p.x[rowg*TENC + r];
      float hA, hB;
      cellpair(X0, b0s, wih0s, xr, crow, dp, c0a, c0b, hA, hB);
      storeh(h0buf + (r&1)*BH, rowg, cold, hA, hB);
    }
    if (r >= 1){
      float hA, hB;
      cellpair(X1, b1s, wih0s, 0.f, crow, dp, c1a, c1b, hA, hB);
      storeh(h1buf + ((r-1)&1)*BH, rowg, cold, hA, hB);
    }
    ++ev;
    gbar(flags, g, j, lane, tid, ev);
  }

  // ---- switch to decoder weights ----
  __syncthreads();
  if (tid < 64){
    int gt = tid >> 4, d = tid & 15;
    int grow = gt*256 + j*16 + d;
    wih0s[tid] = p.dWih0[grow];
    b0s[tid] = p.dBih0[grow] + p.dBhh0[grow];
    b1s[tid] = p.dBih1[grow] + p.dBhh1[grow];
  }
  {
    int grow = n*256 + j*16 + (lane & 15);
    int kb = 8*(lane>>4);
    #pragma unroll
    for (int kt=0; kt<8; ++kt){
      B0[kt]  = loadWfrag(p.dWhh0, grow, kt*32 + kb);
      B1i[kt] = loadWfrag(p.dWih1, grow, kt*32 + kb);
      B1h[kt] = loadWfrag(p.dWhh1, grow, kt*32 + kb);
    }
  }
  __syncthreads();

  // ================= DECODER ================================================
  for (int t = 0; t < HORIZ; ++t){
    // --- L0 ---
    stage_tile(A0, h0buf + ((t+1)&1)*BH, g, tid);   // h0(t-1); t=0 -> enc h0(335)
    __syncthreads();

    f32x4 acc0[2] = {{0.f,0.f,0.f,0.f},{0.f,0.f,0.f,0.f}};
    #pragma unroll
    for (int kt=0; kt<8; ++kt){
      #pragma unroll
      for (int m=0; m<2; ++m){
        f16x8 a = *(const f16x8*)(A0 + ((kt*4 + (mh*2+m))*64 + lane)*16);
        acc0[m] = __builtin_amdgcn_mfma_f32_16x16x32_f16(a, B0[kt], acc0[m], 0,0,0);
      }
    }
    #pragma unroll
    for (int m=0; m<2; ++m){
      int rb = mh*32 + m*16 + 4*(lane>>4);
      #pragma unroll
      for (int q=0; q<4; ++q) X0[(n*64 + rb + q)*16 + (lane&15)] = acc0[m][q];
    }
    __syncthreads();

    float inp = (t == 0) ? p.x[rowg*TENC + (TENC-1)]
                         : aldf(&predb[((t+1)&1)*BSZ + rowg]);
    {
      float hA, hB;
      cellpair(X0, b0s, wih0s, inp, crow, dp, c0a, c0b, hA, hB);
      storeh(h0buf + (t&1)*BH, rowg, cold, hA, hB);
    }
    if (t > 0 && j == 0 && (tid & 7) == 0) p.out[rowg*HORIZ + (t-1)] = inp;
    ++ev;
    gbar(flags, g, j, lane, tid, ev);

    // --- L1 ---
    stage_tile(A0, h0buf + (t&1)*BH,     g, tid);   // h0(t) (fresh)
    stage_tile(A1, h1buf + ((t+1)&1)*BH, g, tid);   // h1(t-1)
    __syncthreads();

    f32x4 acc1[2] = {{0.f,0.f,0.f,0.f},{0.f,0.f,0.f,0.f}};
    #pragma unroll
    for (int kt=0; kt<8; ++kt){
      #pragma unroll
      for (int m=0; m<2; ++m){
        f16x8 a0 = *(const f16x8*)(A0 + ((kt*4 + (mh*2+m))*64 + lane)*16);
        acc1[m] = __builtin_amdgcn_mfma_f32_16x16x32_f16(a0, B1i[kt], acc1[m], 0,0,0);
        f16x8 a1 = *(const f16x8*)(A1 + ((kt*4 + (mh*2+m))*64 + lane)*16);
        acc1[m] = __builtin_amdgcn_mfma_f32_16x16x32_f16(a1, B1h[kt], acc1[m], 0,0,0);
      }
    }
    #pragma unroll
    for (int m=0; m<2; ++m){
      int rb = mh*32 + m*16 + 4*(lane>>4);
      #pragma unroll
      for (int q=0; q<4; ++q) X1[(n*64 + rb + q)*16 + (lane&15)] = acc1[m][q];
    }
    __syncthreads();

    {
      float hA, hB;
      cellpair(X1, b1s, wih0s, 0.f, crow, dp, c1a, c1b, hA, hB);
      storeh(h1buf + (t&1)*BH, rowg, cold, hA, hB);
      // partial pred over this CU's 16 dims: reduce the 8 threads of a row
      float pp = fcWs[dp]*hA + fcWs[dp+1]*hB;
      pp += __shfl_xor(pp, 1);
      pp += __shfl_xor(pp, 2);
      pp += __shfl_xor(pp, 4);
      if ((tid & 7) == 0){
        float v = pp + (j == 0 ? fcbs[0] : 0.f);
        __hip_atomic_fetch_add(&predb[(t&1)*BSZ + rowg], v,
                               __ATOMIC_RELAXED, __HIP_MEMORY_SCOPE_AGENT);
        if (j == 0) astf(&predb[((t+1)&1)*BSZ + rowg], 0.f); // recycle other parity
      }
    }
    ++ev;
    gbar(flags, g, j, lane, tid, ev);
  }

  // final column
  if (j == 0 && (tid & 7) == 0){
    float v = aldf(&predb[((HORIZ-1)&1)*BSZ + rowg]);
    p.out[rowg*HORIZ + (HORIZ-1)] = v;
  }
}

extern "C" void kernel_launch(void* const* d_in, const int* in_sizes, int n_in,
                              void* d_out, int out_size, void* d_ws, size_t ws_size,
                              hipStream_t stream) {
  (void)in_sizes; (void)n_in; (void)out_size;
  if (ws_size < (size_t)WS_TOTAL) return;  // fail visibly (poisoned output)

  P prm;
  prm.x     = (const float*)d_in[0];
  prm.eWih0 = (const float*)d_in[1];  prm.eWhh0 = (const float*)d_in[2];
  prm.eBih0 = (const float*)d_in[3];  prm.eBhh0 = (const float*)d_in[4];
  prm.eWih1 = (const float*)d_in[5];  prm.eWhh1 = (const float*)d_in[6];
  prm.eBih1 = (const float*)d_in[7];  prm.eBhh1 = (const float*)d_in[8];
  prm.dWih0 = (const float*)d_in[9];  prm.dWhh0 = (const float*)d_in[10];
  prm.dBih0 = (const float*)d_in[11]; prm.dBhh0 = (const float*)d_in[12];
  prm.dWih1 = (const float*)d_in[13]; prm.dWhh1 = (const float*)d_in[14];
  prm.dBih1 = (const float*)d_in[15]; prm.dBhh1 = (const float*)d_in[16];
  prm.fcW   = (const float*)d_in[17]; prm.fcB   = (const float*)d_in[18];
  prm.out   = (float*)d_out;
  prm.ws    = (char*)d_ws;

  hipLaunchKernelGGL(initk, dim3(512), dim3(256), 0, stream, (char*)d_ws);

  hipFuncSetAttribute((const void*)lstm_main,
                      hipFuncAttributeMaxDynamicSharedMemorySize, LDS_TOTAL);
  void* args[] = { &prm };
  hipLaunchCooperativeKernel((const void*)lstm_main, dim3(256), dim3(512),
                             args, LDS_TOTAL, stream);
}

// Round 3
// 4033.836 us; speedup vs baseline: 1.0451x; 1.0451x over previous
//
#include <hip/hip_runtime.h>

#define HIDDEN 256
#define TENC 336
#define HORIZ 168
#define BSZ 1024
#define BH (BSZ*HIDDEN)

typedef _Float16 f16;
typedef f16 f16x8 __attribute__((ext_vector_type(8)));
typedef float f32x4 __attribute__((ext_vector_type(4)));
typedef unsigned int u32;
typedef unsigned long long u64;

// ---- workspace layout ----
#define H0_OFF 0
#define H1_OFF (2*BH*2)                  // 1 MiB
#define PP_OFF (H1_OFF + 2*BH*2)         // 2 MiB : pred partials [1024][16] f32
#define CNT_OFF (PP_OFF + BSZ*16*4)      // +64 KiB : 16 group counters, 128B apart
#define WS_TOTAL (CNT_OFF + 16*128)

// ---- LDS layout ----
#define LDS_A0 0
#define LDS_A1 32768
#define LDS_X0 65536
#define XSTRIDE 18
#define LDS_X1 (LDS_X0 + 256*XSTRIDE*4)
#define LDS_SM (LDS_X1 + 256*XSTRIDE*4)
#define LDS_TOTAL (LDS_SM + 1024)

__device__ __forceinline__ float sigm(float x){ return 1.0f/(1.0f+__expf(-x)); }
__device__ __forceinline__ float tanh_f(float x){ return 2.0f/(1.0f+__expf(-2.0f*x)) - 1.0f; }

// ---- proven agent-scope primitives (R1 semantics) ----
__device__ __forceinline__ u64 ald64(const void* p){
  return __hip_atomic_load((const u64*)p, __ATOMIC_RELAXED, __HIP_MEMORY_SCOPE_AGENT);
}
__device__ __forceinline__ u32 ald32(const u32* p){
  return __hip_atomic_load(p, __ATOMIC_RELAXED, __HIP_MEMORY_SCOPE_AGENT);
}
__device__ __forceinline__ void ast32(u32* p, u32 v){
  __hip_atomic_store(p, v, __ATOMIC_RELAXED, __HIP_MEMORY_SCOPE_AGENT);
}

// B-fragment for v_mfma_f32_16x16x32_f16: lane holds W[col=l&15][k..k+7], k=kt*32+8*(l>>4)
__device__ __forceinline__ f16x8 loadWfrag(const float* W, int grow, int k){
  const float* p = W + grow*HIDDEN + k;
  float4 lo = *(const float4*)p;
  float4 hi = *(const float4*)(p+4);
  f16x8 r;
  r[0]=(f16)lo.x; r[1]=(f16)lo.y; r[2]=(f16)lo.z; r[3]=(f16)lo.w;
  r[4]=(f16)hi.x; r[5]=(f16)hi.y; r[6]=(f16)hi.z; r[7]=(f16)hi.w;
  return r;
}

// slot s -> fragment address math shared by all stagers
__device__ __forceinline__ const f16* slot_src(const f16* base, int g, int s){
  int l = s & 63, f = s >> 6;
  int kt = f >> 2, mt = f & 3;
  int row = g*64 + mt*16 + (l&15);
  int k = kt*32 + 8*(l>>4);
  return base + row*HIDDEN + k;
}

// stage one 64x256 f16 h-tile: issue all 8 loads, then commit to LDS
__device__ __forceinline__ void stage_tile(char* dst, const f16* src_base, int g, int tid){
  u64 v[8];
  #pragma unroll
  for (int i=0;i<4;++i){
    const f16* src = slot_src(src_base, g, tid + 512*i);
    v[2*i]   = ald64(src);
    v[2*i+1] = ald64(src+4);
  }
  #pragma unroll
  for (int i=0;i<4;++i){
    int s = tid + 512*i;
    *(u64*)(dst + s*16)     = v[2*i];
    *(u64*)(dst + s*16 + 8) = v[2*i+1];
  }
}

// stage two tiles with all 16 loads in flight before any commit
__device__ __forceinline__ void stage2(char* dA, const f16* sA, char* dB, const f16* sB,
                                       int g, int tid){
  u64 va[8], vb[8];
  #pragma unroll
  for (int i=0;i<4;++i){
    const f16* src = slot_src(sA, g, tid + 512*i);
    va[2*i]   = ald64(src);
    va[2*i+1] = ald64(src+4);
  }
  #pragma unroll
  for (int i=0;i<4;++i){
    const f16* src = slot_src(sB, g, tid + 512*i);
    vb[2*i]   = ald64(src);
    vb[2*i+1] = ald64(src+4);
  }
  #pragma unroll
  for (int i=0;i<4;++i){
    int s = tid + 512*i;
    *(u64*)(dA + s*16)     = va[2*i];
    *(u64*)(dA + s*16 + 8) = va[2*i+1];
    *(u64*)(dB + s*16)     = vb[2*i];
    *(u64*)(dB + s*16 + 8) = vb[2*i+1];
  }
}

__device__ __forceinline__ void cellpair(const float* X, const float* bs, const float* wih, float xr,
                                         int crow, int dp, float& ca, float& cb, float& hA, float& hB){
  float iA = X[(0*64+crow)*XSTRIDE+dp  ] + bs[dp]      + xr*wih[dp];
  float iB = X[(0*64+crow)*XSTRIDE+dp+1] + bs[dp+1]    + xr*wih[dp+1];
  float fA = X[(1*64+crow)*XSTRIDE+dp  ] + bs[16+dp]   + xr*wih[16+dp];
  float fB = X[(1*64+crow)*XSTRIDE+dp+1] + bs[16+dp+1] + xr*wih[16+dp+1];
  float gA = X[(2*64+crow)*XSTRIDE+dp  ] + bs[32+dp]   + xr*wih[32+dp];
  float gB = X[(2*64+crow)*XSTRIDE+dp+1] + bs[32+dp+1] + xr*wih[32+dp+1];
  float oA = X[(3*64+crow)*XSTRIDE+dp  ] + bs[48+dp]   + xr*wih[48+dp];
  float oB = X[(3*64+crow)*XSTRIDE+dp+1] + bs[48+dp+1] + xr*wih[48+dp+1];
  ca = sigm(fA)*ca + sigm(iA)*tanh_f(gA);
  cb = sigm(fB)*cb + sigm(iB)*tanh_f(gB);
  hA = sigm(oA)*tanh_f(ca);
  hB = sigm(oB)*tanh_f(cb);
}

__device__ __forceinline__ void storeh(f16* base, int rowg, int col, float hA, float hB){
  u32 pk = (u32)__builtin_bit_cast(unsigned short, (f16)hA)
         | ((u32)__builtin_bit_cast(unsigned short, (f16)hB) << 16);
  ast32((u32*)(base + rowg*HIDDEN + col), pk);
}

// group barrier: per-group arrival counter (one atomicAdd per block), wave0 polls one line.
// __syncthreads() before arrival drains all waves' (compiler-tracked) h-stores.
__device__ __forceinline__ void gbar(u32* cnt, int tid, u32 target){
  __syncthreads();
  if (tid == 0)
    (void)__hip_atomic_fetch_add(cnt, 1u, __ATOMIC_RELAXED, __HIP_MEMORY_SCOPE_AGENT);
  if (tid < 64){
    for (int it = 0; it < (1<<17); ++it){
      if (ald32(cnt) >= target) break;
    }
  }
  __syncthreads();
}

struct P {
  const float *x;
  const float *eWih0,*eWhh0,*eBih0,*eBhh0,*eWih1,*eWhh1,*eBih1,*eBhh1;
  const float *dWih0,*dWhh0,*dBih0,*dBhh0,*dWih1,*dWhh1,*dBih1,*dBhh1;
  const float *fcW,*fcB;
  float* out;
  char* ws;
};

__global__ void initk(char* ws){
  u32* p = (u32*)ws;
  size_t total = (size_t)WS_TOTAL / 4;
  for (size_t k = (size_t)blockIdx.x*blockDim.x + threadIdx.x; k < total;
       k += (size_t)gridDim.x*blockDim.x) p[k] = 0u;
}

__global__ __launch_bounds__(512, 2) void lstm_main(P p){
  const int tid  = threadIdx.x;
  const int lane = tid & 63;
  const int w    = tid >> 6;      // wave 0..7
  const int n    = w & 3;         // gate type (i,f,g,o)
  const int mh   = w >> 2;        // row-half 0/1
  const int blk  = blockIdx.x;
  const int g    = blk & 15;      // row group
  const int j    = blk >> 4;      // gate-slice member 0..15

  extern __shared__ __align__(16) char smem[];
  char*  A0 = smem + LDS_A0;
  char*  A1 = smem + LDS_A1;
  float* X0 = (float*)(smem + LDS_X0);
  float* X1 = (float*)(smem + LDS_X1);
  float* wih0s = (float*)(smem + LDS_SM);  // [64] gate-major
  float* b0s   = wih0s + 64;               // [64]
  float* b1s   = wih0s + 128;              // [64]
  float* fcWs  = wih0s + 192;              // [16]
  float* fcbs  = wih0s + 208;              // [1]

  f16*   h0buf = (f16*)(p.ws + H0_OFF);
  f16*   h1buf = (f16*)(p.ws + H1_OFF);
  float* ppart = (float*)(p.ws + PP_OFF);
  u32*   cnt   = (u32*)(p.ws + CNT_OFF) + g*32;   // one line per group

  const int crow = tid >> 3;           // 0..63 row in group
  const int dp   = (tid & 7) * 2;      // dim pair in slice
  const int rowg = g*64 + crow;        // global batch row
  const int cold = j*16 + dp;          // global h column of this thread's pair

  float c0a=0.f, c0b=0.f, c1a=0.f, c1b=0.f;

  // ---- encoder tables ----
  if (tid < 64){
    int gt = tid >> 4, d = tid & 15;
    int grow = gt*256 + j*16 + d;
    wih0s[tid] = p.eWih0[grow];
    b0s[tid] = p.eBih0[grow] + p.eBhh0[grow];
    b1s[tid] = p.eBih1[grow] + p.eBhh1[grow];
  }
  if (tid < 16) fcWs[tid] = p.fcW[j*16 + tid];
  if (tid == 0) fcbs[0] = p.fcB[0];

  // ---- encoder weight fragments (VGPR-resident) ----
  f16x8 B0[8], B1i[8], B1h[8];
  {
    int grow = n*256 + j*16 + (lane & 15);
    int kb = 8*(lane>>4);
    #pragma unroll
    for (int kt=0; kt<8; ++kt){
      B0[kt]  = loadWfrag(p.eWhh0, grow, kt*32 + kb);
      B1i[kt] = loadWfrag(p.eWih1, grow, kt*32 + kb);
      B1h[kt] = loadWfrag(p.eWhh1, grow, kt*32 + kb);
    }
  }
  __syncthreads();

  u32 ev = 0;

  // ================= ENCODER: round r computes cell0(r) and cell1(r-1) ======
  for (int r = 0; r <= TENC; ++r){
    float xr = (r < TENC) ? p.x[rowg*TENC + r] : 0.f;
    stage2(A0, h0buf + ((r+1)&1)*BH, A1, h1buf + (r&1)*BH, g, tid);
    __syncthreads();

    f32x4 acc0[2] = {{0.f,0.f,0.f,0.f},{0.f,0.f,0.f,0.f}};
    f32x4 acc1[2] = {{0.f,0.f,0.f,0.f},{0.f,0.f,0.f,0.f}};
    #pragma unroll
    for (int kt=0; kt<8; ++kt){
      #pragma unroll
      for (int m=0; m<2; ++m){
        f16x8 a = *(const f16x8*)(A0 + ((kt*4 + (mh*2+m))*64 + lane)*16);
        acc0[m] = __builtin_amdgcn_mfma_f32_16x16x32_f16(a, B0[kt],  acc0[m], 0,0,0);
        acc1[m] = __builtin_amdgcn_mfma_f32_16x16x32_f16(a, B1i[kt], acc1[m], 0,0,0);
      }
    }
    #pragma unroll
    for (int kt=0; kt<8; ++kt){
      #pragma unroll
      for (int m=0; m<2; ++m){
        f16x8 a = *(const f16x8*)(A1 + ((kt*4 + (mh*2+m))*64 + lane)*16);
        acc1[m] = __builtin_amdgcn_mfma_f32_16x16x32_f16(a, B1h[kt], acc1[m], 0,0,0);
      }
    }

    #pragma unroll
    for (int m=0; m<2; ++m){
      int rb = mh*32 + m*16 + 4*(lane>>4);
      #pragma unroll
      for (int q=0; q<4; ++q){
        X0[(n*64 + rb + q)*XSTRIDE + (lane&15)] = acc0[m][q];
        X1[(n*64 + rb + q)*XSTRIDE + (lane&15)] = acc1[m][q];
      }
    }
    __syncthreads();

    if (r < TENC){
      float hA, hB;
      cellpair(X0, b0s, wih0s, xr, crow, dp, c0a, c0b, hA, hB);
      storeh(h0buf + (r&1)*BH, rowg, cold, hA, hB);
    }
    if (r >= 1){
      float hA, hB;
      cellpair(X1, b1s, wih0s, 0.f, crow, dp, c1a, c1b, hA, hB);
      storeh(h1buf + ((r-1)&1)*BH, rowg, cold, hA, hB);
    }
    ++ev;
    gbar(cnt, tid, 16u*ev);
  }

  // ---- switch to decoder weights ----
  __syncthreads();
  if (tid < 64){
    int gt = tid >> 4, d = tid & 15;
    int grow = gt*256 + j*16 + d;
    wih0s[tid] = p.dWih0[grow];
    b0s[tid] = p.dBih0[grow] + p.dBhh0[grow];
    b1s[tid] = p.dBih1[grow] + p.dBhh1[grow];
  }
  {
    int grow = n*256 + j*16 + (lane & 15);
    int kb = 8*(lane>>4);
    #pragma unroll
    for (int kt=0; kt<8; ++kt){
      B0[kt]  = loadWfrag(p.dWhh0, grow, kt*32 + kb);
      B1i[kt] = loadWfrag(p.dWih1, grow, kt*32 + kb);
      B1h[kt] = loadWfrag(p.dWhh1, grow, kt*32 + kb);
    }
  }
  __syncthreads();

  // ================= DECODER ================================================
  for (int t = 0; t < HORIZ; ++t){
    // --- phase 1: L0 cell + Whh1*h1(t-1) head start ---
    u64 ppv = 0;
    float xlast = 0.f;
    if (t == 0) xlast = p.x[rowg*TENC + (TENC-1)];
    else        ppv   = ald64(ppart + rowg*16 + (tid&7)*2);   // hidden under MFMAs

    stage2(A0, h0buf + ((t+1)&1)*BH, A1, h1buf + ((t+1)&1)*BH, g, tid);
    __syncthreads();

    f32x4 acc0[2] = {{0.f,0.f,0.f,0.f},{0.f,0.f,0.f,0.f}};
    f32x4 acc1[2] = {{0.f,0.f,0.f,0.f},{0.f,0.f,0.f,0.f}};
    #pragma unroll
    for (int kt=0; kt<8; ++kt){
      #pragma unroll
      for (int m=0; m<2; ++m){
        f16x8 a0 = *(const f16x8*)(A0 + ((kt*4 + (mh*2+m))*64 + lane)*16);
        acc0[m] = __builtin_amdgcn_mfma_f32_16x16x32_f16(a0, B0[kt],  acc0[m], 0,0,0);
        f16x8 a1 = *(const f16x8*)(A1 + ((kt*4 + (mh*2+m))*64 + lane)*16);
        acc1[m] = __builtin_amdgcn_mfma_f32_16x16x32_f16(a1, B1h[kt], acc1[m], 0,0,0);
      }
    }
    #pragma unroll
    for (int m=0; m<2; ++m){
      int rb = mh*32 + m*16 + 4*(lane>>4);
      #pragma unroll
      for (int q=0; q<4; ++q) X0[(n*64 + rb + q)*XSTRIDE + (lane&15)] = acc0[m][q];
    }
    __syncthreads();

    float inp;
    if (t == 0){
      inp = xlast;
    } else {
      float a = __builtin_bit_cast(float, (u32)(ppv & 0xffffffffull));
      float b = __builtin_bit_cast(float, (u32)(ppv >> 32));
      float s = a + b;
      s += __shfl_xor(s, 1);
      s += __shfl_xor(s, 2);
      s += __shfl_xor(s, 4);
      inp = s + fcbs[0];
    }
    {
      float hA, hB;
      cellpair(X0, b0s, wih0s, inp, crow, dp, c0a, c0b, hA, hB);
      storeh(h0buf + (t&1)*BH, rowg, cold, hA, hB);
    }
    if (t > 0 && j == 0 && (tid & 7) == 0) p.out[rowg*HORIZ + (t-1)] = inp;
    ++ev;
    gbar(cnt, tid, 16u*ev);

    // --- phase 2: L1 cell (acc1 already holds Whh1*h1(t-1)) ---
    stage_tile(A0, h0buf + (t&1)*BH, g, tid);   // fresh h0(t)
    __syncthreads();

    #pragma unroll
    for (int kt=0; kt<8; ++kt){
      #pragma unroll
      for (int m=0; m<2; ++m){
        f16x8 a0 = *(const f16x8*)(A0 + ((kt*4 + (mh*2+m))*64 + lane)*16);
        acc1[m] = __builtin_amdgcn_mfma_f32_16x16x32_f16(a0, B1i[kt], acc1[m], 0,0,0);
      }
    }
    #pragma unroll
    for (int m=0; m<2; ++m){
      int rb = mh*32 + m*16 + 4*(lane>>4);
      #pragma unroll
      for (int q=0; q<4; ++q) X1[(n*64 + rb + q)*XSTRIDE + (lane&15)] = acc1[m][q];
    }
    __syncthreads();

    {
      float hA, hB;
      cellpair(X1, b1s, wih0s, 0.f, crow, dp, c1a, c1b, hA, hB);
      storeh(h1buf + (t&1)*BH, rowg, cold, hA, hB);
      float pp = fcWs[dp]*hA + fcWs[dp+1]*hB;
      pp += __shfl_xor(pp, 1);
      pp += __shfl_xor(pp, 2);
      pp += __shfl_xor(pp, 4);
      if ((tid & 7) == 0)
        ast32((u32*)(ppart + rowg*16 + j), __builtin_bit_cast(u32, pp));
    }
    ++ev;
    gbar(cnt, tid, 16u*ev);
  }

  // final column: pred(HORIZ-1) from the last pp partials
  if (j == 0){
    u64 ppv = ald64(ppart + rowg*16 + (tid&7)*2);
    float a = __builtin_bit_cast(float, (u32)(ppv & 0xffffffffull));
    float b = __builtin_bit_cast(float, (u32)(ppv >> 32));
    float s = a + b;
    s += __shfl_xor(s, 1);
    s += __shfl_xor(s, 2);
    s += __shfl_xor(s, 4);
    if ((tid & 7) == 0) p.out[rowg*HORIZ + (HORIZ-1)] = s + fcbs[0];
  }
}

extern "C" void kernel_launch(void* const* d_in, const int* in_sizes, int n_in,
                              void* d_out, int out_size, void* d_ws, size_t ws_size,
                              hipStream_t stream) {
  (void)in_sizes; (void)n_in; (void)out_size;
  if (ws_size < (size_t)WS_TOTAL) return;  // fail visibly (poisoned output)

  P prm;
  prm.x     = (const float*)d_in[0];
  prm.eWih0 = (const float*)d_in[1];  prm.eWhh0 = (const float*)d_in[2];
  prm.eBih0 = (const float*)d_in[3];  prm.eBhh0 = (const float*)d_in[4];
  prm.eWih1 = (const float*)d_in[5];  prm.eWhh1 = (const float*)d_in[6];
  prm.eBih1 = (const float*)d_in[7];  prm.eBhh1 = (const float*)d_in[8];
  prm.dWih0 = (const float*)d_in[9];  prm.dWhh0 = (const float*)d_in[10];
  prm.dBih0 = (const float*)d_in[11]; prm.dBhh0 = (const float*)d_in[12];
  prm.dWih1 = (const float*)d_in[13]; prm.dWhh1 = (const float*)d_in[14];
  prm.dBih1 = (const float*)d_in[15]; prm.dBhh1 = (const float*)d_in[16];
  prm.fcW   = (const float*)d_in[17]; prm.fcB   = (const float*)d_in[18];
  prm.out   = (float*)d_out;
  prm.ws    = (char*)d_ws;

  hipLaunchKernelGGL(initk, dim3(512), dim3(256), 0, stream, (char*)d_ws);

  hipFuncSetAttribute((const void*)lstm_main,
                      hipFuncAttributeMaxDynamicSharedMemorySize, LDS_TOTAL);
  void* args[] = { &prm };
  hipLaunchCooperativeKernel((const void*)lstm_main, dim3(256), dim3(512),
                             args, LDS_TOTAL, stream);
}